// Round 2
// baseline (3528.011 us; speedup 1.0000x reference)
//
#include <hip/hip_runtime.h>
#include <math.h>

#define LOG0f (-1.0e30f)
#define ACTIVE_TH (-1.0e29f)
#define PRUNE_TH (-9.0f)
#define BW 8
#define VCAB 128
#define HSZ 4096
#define HMASK (HSZ - 1)
#define MAXN 2052
#define HEMPTY 0xFFFFFFFFu

// JAX-exact logaddexp: max + log1p(exp(-|a-b|)) in f32
__device__ __forceinline__ float lae(float a, float b) {
    float mx = fmaxf(a, b);
    float d = fabsf(a - b);
    return mx + log1pf(expf(-d));
}
// monotonic float->uint transform (order-preserving)
__device__ __forceinline__ unsigned mono(float f) {
    unsigned u = __float_as_uint(f);
    return (u & 0x80000000u) ? ~u : (u | 0x80000000u);
}
__device__ __forceinline__ float mono_inv(unsigned m) {
    unsigned u = (m & 0x80000000u) ? (m & 0x7FFFFFFFu) : ~m;
    return __uint_as_float(u);
}

// 64-lane max of (hi,lo) u64 keys on the VALU pipe; result broadcast to ALL lanes.
// 4x row_ror DPP levels (16-lane rotate-max) + permlane16/32 swaps for cross-row.
#define ROR_STEP(CTRL)                                                                  \
    do {                                                                                \
        unsigned h2 = (unsigned)__builtin_amdgcn_update_dpp(0, (int)hi, (CTRL), 0xf, 0xf, false); \
        unsigned l2 = (unsigned)__builtin_amdgcn_update_dpp(0, (int)lo, (CTRL), 0xf, 0xf, false); \
        bool g = (h2 > hi) || (h2 == hi && l2 > lo);                                    \
        hi = g ? h2 : hi;                                                               \
        lo = g ? l2 : lo;                                                               \
    } while (0)

__device__ __forceinline__ void wave_max64(unsigned &hi, unsigned &lo) {
    ROR_STEP(0x121);  // row_ror:1
    ROR_STEP(0x122);  // row_ror:2
    ROR_STEP(0x124);  // row_ror:4
    ROR_STEP(0x128);  // row_ror:8  -> every lane holds its 16-row max
    {   // combine rows 0<->1, 2<->3
        unsigned ah = hi, ch = hi, al = lo, cl = lo;
        asm("v_permlane16_swap_b32 %0, %1" : "+v"(ah), "+v"(ch));
        asm("v_permlane16_swap_b32 %0, %1" : "+v"(al), "+v"(cl));
        bool g = (ch > ah) || (ch == ah && cl > al);
        hi = g ? ch : ah;
        lo = g ? cl : al;
    }
    {   // combine halves 0<->1
        unsigned ah = hi, ch = hi, al = lo, cl = lo;
        asm("v_permlane32_swap_b32 %0, %1" : "+v"(ah), "+v"(ch));
        asm("v_permlane32_swap_b32 %0, %1" : "+v"(al), "+v"(cl));
        bool g = (ch > ah) || (ch == ah && cl > al);
        hi = g ? ch : ah;
        lo = g ? cl : al;
    }
}

__global__ __launch_bounds__(64)
void ctc_beam_kernel(const float* __restrict__ probs, const int* __restrict__ lengths,
                     const int* __restrict__ blank_p, int* __restrict__ out_seq,
                     int* __restrict__ out_len, int T) {
    __shared__ unsigned hsh[HSZ];       // dedup map (parent,label)->node: (hkey<<12)|id
    __shared__ unsigned nodeinfo[MAXN]; // (parent<<7)|label per node id
    __shared__ int sh_seq[256];

    const int lane = threadIdx.x;
    const int b = blockIdx.x;
    const int blank = blank_p[0];
    const int length = lengths[b];
    const float* __restrict__ P = probs + (size_t)b * T * VCAB;

    for (int i = lane; i < HSZ; i += 64) hsh[i] = HEMPTY;
    __syncthreads();

    // replicated beam state: identical copy in every lane, compile-time indexed only
    float pb[BW], pnb[BW];
    int len8[BW], last8[BW];
    unsigned node8[BW], par8[BW];
#pragma unroll
    for (int i = 0; i < BW; ++i) {
        pb[i] = (i == 0) ? 0.0f : LOG0f;  // root: blank prob = log(1)
        pnb[i] = LOG0f;
        len8[i] = 0;
        last8[i] = blank;
        node8[i] = 0;
        par8[i] = HEMPTY;
    }

    // lane owns labels {lane, lane+64}; software-pipelined row loads
    float prL = P[lane];
    float prH = P[64 + lane];

    for (int t = 0; t < length; ++t) {
        float nprL = 0.f, nprH = 0.f;
        if (t + 1 < length) {
            nprL = P[(size_t)(t + 1) * VCAB + lane];
            nprH = P[(size_t)(t + 1) * VCAB + 64 + lane];
        }

        // gathers from registers (ds_bpermute), no LDS staging
        float prB;
        {
            float a = __shfl(prL, blank & 63, 64), c = __shfl(prH, blank & 63, 64);
            prB = (blank < 64) ? a : c;
        }
        float prLast[BW];
#pragma unroll
        for (int i = 0; i < BW; ++i) {
            float a = __shfl(prL, last8[i] & 63, 64), c = __shfl(prH, last8[i] & 63, 64);
            prLast[i] = (last8[i] < 64) ? a : c;
        }

        // totals / act
        float ptot[BW];
        bool act8[BW];
#pragma unroll
        for (int i = 0; i < BW; ++i) {
            ptot[i] = lae(pb[i], pnb[i]);
            act8[i] = ptot[i] > ACTIVE_TH;
        }

        // parent match by node-id identity (ids are content-unique via dedup hash)
        float pprev[BW];
        unsigned long long kidsAll = 0ull;  // bit (j*8+i): beam i's parent is beam j
#pragma unroll
        for (int i = 0; i < BW; ++i) {
            bool gate = act8[i] && (len8[i] > 0);
            float pp = LOG0f;
#pragma unroll
            for (int j = 0; j < BW; ++j) {
                if (j == i) continue;
                bool m = gate && act8[j] && (node8[j] == par8[i]);
                if (m) pp = (last8[i] == last8[j]) ? pb[j] : ptot[j];
                kidsAll |= m ? (1ull << (j * 8 + i)) : 0ull;
            }
            pprev[i] = pp;
        }

        float contb[BW], contnb[BW];
#pragma unroll
        for (int i = 0; i < BW; ++i) {
            contb[i] = ptot[i] + prB;
            contnb[i] = (len8[i] > 0) ? (lae(pnb[i], pprev[i]) + prLast[i]) : LOG0f;
        }

        // per-lane label-match masks: bit a set iff last8[a]==v
        unsigned lmL = 0, lmH = 0;
#pragma unroll
        for (int a = 0; a < BW; ++a) {
            lmL |= (last8[a] == lane) ? (1u << a) : 0u;
            lmH |= (last8[a] == lane + 64) ? (1u << a) : 0u;
        }

        // candidate keys: 16 extensions per lane + 1 continuation on lanes 0..7
        // ref index space: [0..7]=continuations, [8..8+1024)=extensions i*V+v
        unsigned kh[17], kl[17];
#pragma unroll
        for (int k = 0; k < 16; ++k) {
            const int i = k >> 1;
            const bool hiv = k & 1;
            const int v = hiv ? (lane + 64) : lane;
            const float pv = hiv ? prH : prL;
            unsigned kid = (unsigned)(kidsAll >> (i * 8)) & 0xFFu;
            bool childin = (kid & (hiv ? lmH : lmL)) != 0;
            float prev = (v == last8[i]) ? pb[i] : ptot[i];
            float val = pv + prev;
            bool bad = (v == blank) | (pv <= PRUNE_TH) | (!act8[i]) | childin;
            if (bad) val = LOG0f;
            kh[k] = mono(val);
            kl[k] = ~(8u + (unsigned)(i * VCAB + v));
        }
        {
            float cb = LOG0f, cn = LOG0f;
#pragma unroll
            for (int j = 0; j < BW; ++j) {
                bool m = (lane == j);
                cb = m ? contb[j] : cb;
                cn = m ? contnb[j] : cn;
            }
            float tot = lae(cb, cn);
            kh[16] = (lane < BW) ? mono(tot) : 0u;
            kl[16] = (lane < BW) ? ~(unsigned)lane : 0u;
        }

        // local max
        unsigned mh = 0, ml = 0;
#pragma unroll
        for (int k = 0; k < 17; ++k) {
            bool g = (kh[k] > mh) || (kh[k] == mh && kl[k] > ml);
            mh = g ? kh[k] : mh;
            ml = g ? kl[k] : ml;
        }

        // top-8 selection; per-round winner is broadcast to all lanes by wave_max64
        float npb[BW], npnb[BW];
        int nlen[BW], nlast[BW];
        unsigned nnode[BW], npar[BW];
        unsigned extmask = 0;
        unsigned insPar = 0, insRes = 0;
        int insLab = 0;
#pragma unroll
        for (int r = 0; r < BW; ++r) {
            unsigned bh = mh, bl = ml;
            wave_max64(bh, bl);
            bool own = (mh == bh) && (ml == bl);
            if (own) {  // exactly one lane: remove winner, recompute local max
#pragma unroll
                for (int k = 0; k < 17; ++k)
                    if (kh[k] == bh && kl[k] == bl) { kh[k] = 0; kl[k] = 0; }
                mh = 0; ml = 0;
#pragma unroll
                for (int k = 0; k < 17; ++k) {
                    bool g = (kh[k] > mh) || (kh[k] == mh && kl[k] > ml);
                    mh = g ? kh[k] : mh;
                    ml = g ? kl[k] : ml;
                }
            }
            unsigned sel = ~bl;          // wave-uniform
            float val = mono_inv(bh);
            if (sel < BW) {  // continuation of beam sel
                int s = (int)sel;
#pragma unroll
                for (int j = 0; j < BW; ++j)
                    if (s == j) {
                        npb[r] = contb[j];
                        npnb[r] = contnb[j];
                        nlen[r] = len8[j];
                        nlast[r] = last8[j];
                        nnode[r] = node8[j];
                        npar[r] = par8[j];
                    }
            } else {  // extension (src s, label lab); stored pnb == sort value bitwise
                unsigned e = sel - BW;
                int s = (int)(e >> 7);
                int lab = (int)(e & 127u);
                npb[r] = LOG0f;
                npnb[r] = val;
                nlast[r] = lab;
#pragma unroll
                for (int j = 0; j < BW; ++j)
                    if (s == j) {
                        nlen[r] = len8[j] + 1;
                        npar[r] = node8[j];
                    }
                nnode[r] = 0;  // resolved below via dedup hash
                extmask |= 1u << r;
                if (lane == r) { insPar = npar[r]; insLab = lab; }
            }
        }

        // dedup-hash inserts: lane r handles beam r (deterministic pre-assigned ids)
        if ((extmask >> lane) & 1u) {
            unsigned preid = 1u + 8u * (unsigned)t + (unsigned)lane;
            unsigned hkey = (insPar << 7) | (unsigned)insLab;
            unsigned entry = (hkey << 12) | preid;
            unsigned h = (hkey * 2654435761u) >> 20;
            for (;;) {
                unsigned prev = atomicCAS(&hsh[h], HEMPTY, entry);
                if (prev == HEMPTY) {
                    nodeinfo[preid] = hkey;
                    insRes = preid;
                    break;
                }
                if ((prev >> 12) == hkey) {  // content already exists: reuse node id
                    insRes = prev & 0xFFFu;
                    break;
                }
                h = (h + 1) & HMASK;
            }
        }
#pragma unroll
        for (int r = 0; r < BW; ++r) {
            if ((extmask >> r) & 1u) {  // uniform condition
                unsigned nd = __shfl(insRes, r, 64);
                nnode[r] = nd;
            }
        }

        // commit
#pragma unroll
        for (int i = 0; i < BW; ++i) {
            pb[i] = npb[i];
            pnb[i] = npnb[i];
            len8[i] = nlen[i];
            last8[i] = nlast[i];
            node8[i] = nnode[i];
            par8[i] = npar[i];
        }
        prL = nprL;
        prH = nprH;
    }

    // final argmax of totals (ties -> lowest index), then parent-walk reconstruction
    unsigned fh, fl;
    {
        float cb = LOG0f, cn = LOG0f;
#pragma unroll
        for (int j = 0; j < BW; ++j) {
            bool m = (lane == j);
            cb = m ? pb[j] : cb;
            cn = m ? pnb[j] : cn;
        }
        float tot = lae(cb, cn);
        fh = (lane < BW) ? mono(tot) : 0u;
        fl = (lane < BW) ? ~(unsigned)lane : 0u;
    }
    wave_max64(fh, fl);
    const int best = (int)(~fl);
    int L = 0;
    unsigned c = 0;
#pragma unroll
    for (int j = 0; j < BW; ++j)
        if (best == j) {
            L = len8[j];
            c = node8[j];
        }
    if (lane == 0) {
        for (int k = L - 1; k >= 0; --k) {
            unsigned info = nodeinfo[c];
            sh_seq[k] = (int)(info & 127u);
            c = info >> 7;
        }
    }
    __syncthreads();
    for (int j = lane; j < T; j += 64)
        out_seq[(size_t)b * T + j] = (j < L) ? sh_seq[j] : 0;
    if (lane == 0) out_len[b] = L;
}

extern "C" void kernel_launch(void* const* d_in, const int* in_sizes, int n_in,
                              void* d_out, int out_size, void* d_ws, size_t ws_size,
                              hipStream_t stream) {
    const float* probs = (const float*)d_in[0];
    const int* lengths = (const int*)d_in[1];
    // d_in[2] = beam_width (fixed 8, compiled in); d_in[3] = blank_index
    const int* blank_p = (const int*)d_in[3];
    const int B = in_sizes[1];
    const int T = in_sizes[0] / (B * VCAB);
    int* out = (int*)d_out;
    ctc_beam_kernel<<<B, 64, 0, stream>>>(probs, lengths, blank_p, out,
                                          out + (size_t)B * T, T);
}

// Round 3
// 1523.680 us; speedup vs baseline: 2.3155x; 2.3155x over previous
//
#include <hip/hip_runtime.h>
#include <math.h>

#define LOG0f (-1.0e30f)
#define ACTIVE_TH (-1.0e29f)
#define PRUNE_TH (-9.0f)
#define VCAB 128
#define HSZ 4096
#define HMASK (HSZ - 1)
#define MAXN 2052
#define HEMPTY 0xFFFFFFFFu

// JAX-exact logaddexp: max + log1p(exp(-|a-b|)) in f32
__device__ __forceinline__ float lae(float a, float b) {
    float mx = fmaxf(a, b);
    float d = fabsf(a - b);
    return mx + log1pf(expf(-d));
}
// monotonic float->uint transform (order-preserving)
__device__ __forceinline__ unsigned mono(float f) {
    unsigned u = __float_as_uint(f);
    return (u & 0x80000000u) ? ~u : (u | 0x80000000u);
}
__device__ __forceinline__ float mono_inv(unsigned m) {
    unsigned u = (m & 0x80000000u) ? (m & 0x7FFFFFFFu) : ~m;
    return __uint_as_float(u);
}

// 64-lane max of (hi,lo) u64 keys on the VALU pipe; result broadcast to ALL lanes.
#define ROR_STEP(CTRL)                                                                  \
    do {                                                                                \
        unsigned h2 = (unsigned)__builtin_amdgcn_update_dpp(0, (int)hi, (CTRL), 0xf, 0xf, false); \
        unsigned l2 = (unsigned)__builtin_amdgcn_update_dpp(0, (int)lo, (CTRL), 0xf, 0xf, false); \
        bool g = (h2 > hi) || (h2 == hi && l2 > lo);                                    \
        hi = g ? h2 : hi;                                                               \
        lo = g ? l2 : lo;                                                               \
    } while (0)

__device__ __forceinline__ void wave_max64(unsigned &hi, unsigned &lo) {
    ROR_STEP(0x121);  // row_ror:1
    ROR_STEP(0x122);  // row_ror:2
    ROR_STEP(0x124);  // row_ror:4
    ROR_STEP(0x128);  // row_ror:8  -> every lane holds its 16-row max
    {
        unsigned ah = hi, ch = hi, al = lo, cl = lo;
        asm("v_permlane16_swap_b32 %0, %1" : "+v"(ah), "+v"(ch));
        asm("v_permlane16_swap_b32 %0, %1" : "+v"(al), "+v"(cl));
        bool g = (ch > ah) || (ch == ah && cl > al);
        hi = g ? ch : ah;
        lo = g ? cl : al;
    }
    {
        unsigned ah = hi, ch = hi, al = lo, cl = lo;
        asm("v_permlane32_swap_b32 %0, %1" : "+v"(ah), "+v"(ch));
        asm("v_permlane32_swap_b32 %0, %1" : "+v"(al), "+v"(cl));
        bool g = (ch > ah) || (ch == ah && cl > al);
        hi = g ? ch : ah;
        lo = g ? cl : al;
    }
}

__global__ __launch_bounds__(64)
void ctc_beam_kernel(const float* __restrict__ probs, const int* __restrict__ lengths,
                     const int* __restrict__ blank_p, int* __restrict__ out_seq,
                     int* __restrict__ out_len, int T) {
    __shared__ unsigned hsh[HSZ];        // dedup map (parent,label)->node: (hkey<<12)|id
    __shared__ unsigned nodeinfo[MAXN];  // (parent<<7)|label per node id
    __shared__ int sh_seq[256];

    const int lane = threadIdx.x;
    const int b = blockIdx.x;
    const int blank = blank_p[0];
    const int length = lengths[b];
    const float* __restrict__ P = probs + (size_t)b * T * VCAB;
    const float4* __restrict__ P4 = (const float4*)P;
    const int own = lane & 7;       // beam owned by this lane
    const int slice = lane >> 3;    // vocab slice [slice*16, +16)
    const int vbase = slice * 16;

    for (int i = lane; i < HSZ; i += 64) hsh[i] = HEMPTY;
    __syncthreads();

    // wave-uniform replicated beam metadata (kept scalar via readfirstlane)
    unsigned node8[8], par8[8], len8[8], last8[8];
#pragma unroll
    for (int j = 0; j < 8; ++j) {
        node8[j] = 0; par8[j] = 0xFFFu; len8[j] = 0; last8[j] = (unsigned)blank;
    }
    // per-lane own-beam state
    float pb_own = (own == 0) ? 0.0f : LOG0f;  // root: blank prob = log(1)
    float pnb_own = LOG0f;
    int len_own = 0, last_own = blank;
    unsigned node_own = 0, par_own = 0xFFFu;

    // prefetch row 0: slice (float4 x4) + shuffle layout (labels lane, lane+64)
    float4 s0, s1, s2, s3;
    float prL, prH;
    {
        int base4 = (vbase >> 2);
        s0 = P4[base4]; s1 = P4[base4 + 1]; s2 = P4[base4 + 2]; s3 = P4[base4 + 3];
        prL = P[lane]; prH = P[64 + lane];
    }

    for (int t = 0; t < length; ++t) {
        // prefetch t+1
        float4 n0, n1, n2, n3;
        float nprL = 0.f, nprH = 0.f;
        n0 = n1 = n2 = n3 = make_float4(0.f, 0.f, 0.f, 0.f);
        if (t + 1 < length) {
            int base4 = (t + 1) * 32 + (vbase >> 2);
            n0 = P4[base4]; n1 = P4[base4 + 1]; n2 = P4[base4 + 2]; n3 = P4[base4 + 3];
            nprL = P[(size_t)(t + 1) * VCAB + lane];
            nprH = P[(size_t)(t + 1) * VCAB + 64 + lane];
        }

        // register gathers
        float ga = __shfl(prL, blank & 63, 64), gb = __shfl(prH, blank & 63, 64);
        const float prB = (blank < 64) ? ga : gb;
        float la_ = __shfl(prL, last_own & 63, 64), lb_ = __shfl(prH, last_own & 63, 64);
        const float prLast = (last_own < 64) ? la_ : lb_;

        // totals / act (one parallel lae)
        float ptot_own = lae(pb_own, pnb_own);
        unsigned long long bal = __ballot(ptot_own > ACTIVE_TH);
        unsigned actmask = (unsigned)bal & 0xFFu;
        bool act_own = (actmask >> own) & 1u;

        // own parent match by node-id identity (ids content-faithful via dedup)
        int p_own = 0;
        bool matched = false;
        {
            bool gate = act_own && (len_own > 0);
#pragma unroll
            for (int j = 0; j < 8; ++j) {
                bool m = gate && ((actmask >> j) & 1u) && (node8[j] == par_own);
                if (m) { p_own = j; matched = true; }
            }
        }
        float pbp = __shfl(pb_own, (lane & 56) | p_own, 64);
        float ptp = __shfl(ptot_own, (lane & 56) | p_own, 64);
        int lastp = 0;
#pragma unroll
        for (int j = 0; j < 8; ++j)
            if (p_own == j) lastp = (int)last8[j];
        float pprev = matched ? ((last_own == lastp) ? pbp : ptp) : LOG0f;

        // labels in my slice claimed as existing children of my beam
        unsigned claimed16 = 0;
#pragma unroll
        for (int j = 0; j < 8; ++j) {
            bool mj = ((actmask >> j) & 1u) && act_own && (node_own == par8[j]);
            bool ins = ((last8[j] >> 4) == (unsigned)slice);
            claimed16 |= (mj && ins) ? (1u << (last8[j] & 15u)) : 0u;
        }

        float contb_own = ptot_own + prB;
        float contnb_own = (len_own > 0) ? (lae(pnb_own, pprev) + prLast) : LOG0f;

        // candidate keys: 16 extensions (my beam x my slice) + cont on lanes 0..7
        // ref index space: [0..7]=continuations, [8..8+1024)=extensions i*V+v
        unsigned long long K[17];
#define MAKEK(c, pv)                                                                     \
        {                                                                                \
            int v = vbase + (c);                                                         \
            float prev = (v == last_own) ? pb_own : ptot_own;                            \
            float val = (pv) + prev;                                                     \
            bool bad = (v == blank) | ((pv) <= PRUNE_TH) | (!act_own) |                  \
                       (bool)((claimed16 >> (c)) & 1u);                                  \
            if (bad) val = LOG0f;                                                        \
            K[c] = (((unsigned long long)mono(val)) << 32) |                             \
                   (unsigned)~(8u + (unsigned)(own * VCAB + v));                         \
        }
        MAKEK(0, s0.x) MAKEK(1, s0.y) MAKEK(2, s0.z) MAKEK(3, s0.w)
        MAKEK(4, s1.x) MAKEK(5, s1.y) MAKEK(6, s1.z) MAKEK(7, s1.w)
        MAKEK(8, s2.x) MAKEK(9, s2.y) MAKEK(10, s2.z) MAKEK(11, s2.w)
        MAKEK(12, s3.x) MAKEK(13, s3.y) MAKEK(14, s3.z) MAKEK(15, s3.w)
#undef MAKEK
        {
            float tot = lae(contb_own, contnb_own);
            K[16] = (lane < 8)
                        ? ((((unsigned long long)mono(tot)) << 32) | (unsigned)~(unsigned)lane)
                        : 0ull;
        }

        // local sorted top-3 cache
        unsigned long long m1 = 0ull, m2 = 0ull, m3 = 0ull;
#pragma unroll
        for (int k = 0; k < 17; ++k) {
            unsigned long long key = K[k];
            bool g1 = key > m1, g2 = key > m2, g3 = key > m3;
            unsigned long long t1 = g1 ? key : m1;
            unsigned long long t2 = g1 ? m1 : (g2 ? key : m2);
            m3 = (g1 | g2) ? m2 : (g3 ? key : m3);
            m1 = t1; m2 = t2;
        }

        // top-8 extraction with strictly-decreasing bound W (keys globally unique)
        unsigned long long W = ~0ull;
        unsigned nA[8], nB[8];
        unsigned extmask = 0, insPar = 0, insRes = 0;
        int insLab = 0;
        float npb_own = LOG0f, npnb_own = LOG0f;
#pragma unroll
        for (int r = 0; r < 8; ++r) {
            unsigned long long c = (m1 < W) ? m1 : ((m2 < W) ? m2 : ((m3 < W) ? m3 : 0ull));
            bool exh = !(m3 < W);  // 3 cache entries consumed -> need 4th
            if (__any(exh)) {
                if (exh) {
                    c = 0ull;
#pragma unroll
                    for (int k = 0; k < 17; ++k) {
                        bool g = (K[k] < W) && (K[k] > c);
                        c = g ? K[k] : c;
                    }
                }
            }
            unsigned ch = (unsigned)(c >> 32), cl = (unsigned)(c & 0xFFFFFFFFull);
            wave_max64(ch, cl);
            W = (((unsigned long long)ch) << 32) | cl;
            unsigned ssel = __builtin_amdgcn_readfirstlane(~cl);
            if (ssel < 8u) {  // continuation of beam ssel
                float cb = __shfl(contb_own, (lane & 56) | (int)ssel, 64);
                float cn = __shfl(contnb_own, (lane & 56) | (int)ssel, 64);
                if (own == r) { npb_own = cb; npnb_own = cn; }
                unsigned A = 0, Bv = 0;
#pragma unroll
                for (int j = 0; j < 8; ++j)
                    if (ssel == (unsigned)j) {
                        A = (node8[j] << 12) | par8[j];
                        Bv = (len8[j] << 7) | last8[j];
                    }
                nA[r] = A; nB[r] = Bv;
            } else {  // extension (src s, label lab); stored pnb == sort value bitwise
                unsigned e = ssel - 8u;
                unsigned s = e >> 7, lab = e & 127u;
                float val = mono_inv(ch);
                if (own == r) { npb_own = LOG0f; npnb_own = val; }
                unsigned nd = 0, ln = 0;
#pragma unroll
                for (int j = 0; j < 8; ++j)
                    if (s == (unsigned)j) { nd = node8[j]; ln = len8[j]; }
                nA[r] = (0xFFFu << 12) | nd;  // node patched below; par = nd
                nB[r] = ((ln + 1) << 7) | lab;
                extmask |= (1u << r);
                if ((unsigned)lane == (unsigned)r) { insPar = nd; insLab = (int)lab; }
            }
        }

        // dedup-hash inserts: lane r handles new beam r (deterministic pre-ids)
        if ((extmask >> lane) & 1u) {
            unsigned preid = 1u + 8u * (unsigned)t + (unsigned)lane;
            unsigned hkey = (insPar << 7) | (unsigned)insLab;
            unsigned entry = (hkey << 12) | preid;
            unsigned h = ((hkey * 2654435761u) >> 20) & HMASK;
            for (;;) {
                unsigned prev = atomicCAS(&hsh[h], HEMPTY, entry);
                if (prev == HEMPTY) { nodeinfo[preid] = hkey; insRes = preid; break; }
                if ((prev >> 12) == hkey) { insRes = prev & 0xFFFu; break; }
                h = (h + 1) & HMASK;
            }
        }
        // patch ext node ids + commit wave-uniform arrays
#pragma unroll
        for (int r = 0; r < 8; ++r) {
            unsigned A = nA[r];
            if ((extmask >> r) & 1u) {
                unsigned nd = __shfl(insRes, r, 64);
                A = (nd << 12) | (A & 0xFFFu);
            }
            A = __builtin_amdgcn_readfirstlane(A);
            unsigned Bv = __builtin_amdgcn_readfirstlane(nB[r]);
            node8[r] = A >> 12; par8[r] = A & 0xFFFu;
            len8[r] = Bv >> 7; last8[r] = Bv & 127u;
        }
        // own scalars
#pragma unroll
        for (int j = 0; j < 8; ++j)
            if (own == j) {
                node_own = node8[j]; par_own = par8[j];
                len_own = (int)len8[j]; last_own = (int)last8[j];
            }
        pb_own = npb_own; pnb_own = npnb_own;

        s0 = n0; s1 = n1; s2 = n2; s3 = n3;
        prL = nprL; prH = nprH;
    }

    // final argmax of totals (ties -> lowest index), then parent-walk reconstruction
    unsigned fh, fl;
    {
        float tot = lae(pb_own, pnb_own);
        fh = (lane < 8) ? mono(tot) : 0u;
        fl = (lane < 8) ? ~(unsigned)lane : 0u;
    }
    wave_max64(fh, fl);
    const int best = (int)(~fl);
    int L = 0;
    unsigned c = 0;
#pragma unroll
    for (int j = 0; j < 8; ++j)
        if (best == j) { L = (int)len8[j]; c = node8[j]; }
    if (lane == 0) {
        for (int k = L - 1; k >= 0; --k) {
            unsigned info = nodeinfo[c];
            sh_seq[k] = (int)(info & 127u);
            c = info >> 7;
        }
    }
    __syncthreads();
    for (int j = lane; j < T; j += 64)
        out_seq[(size_t)b * T + j] = (j < L) ? sh_seq[j] : 0;
    if (lane == 0) out_len[b] = L;
}

extern "C" void kernel_launch(void* const* d_in, const int* in_sizes, int n_in,
                              void* d_out, int out_size, void* d_ws, size_t ws_size,
                              hipStream_t stream) {
    const float* probs = (const float*)d_in[0];
    const int* lengths = (const int*)d_in[1];
    // d_in[2] = beam_width (fixed 8, compiled in); d_in[3] = blank_index
    const int* blank_p = (const int*)d_in[3];
    const int B = in_sizes[1];
    const int T = in_sizes[0] / (B * VCAB);
    int* out = (int*)d_out;
    ctc_beam_kernel<<<B, 64, 0, stream>>>(probs, lengths, blank_p, out,
                                          out + (size_t)B * T, T);
}